// Round 1
// baseline (5851.638 us; speedup 1.0000x reference)
//
#include <hip/hip_runtime.h>
#include <math.h>

// ---------------------------------------------------------------------------
// TransformerEncoder: L=3, B=2, S=2048, D=1024, H=16, Dh=64, DF=4096, fp32.
// Round 0: correct fp32 baseline. GEMM = 64x64 tile, 4x4 microtile, LDS-staged.
// Attention = flash-style online softmax, 64 q-rows x 32-key tiles in LDS.
// ---------------------------------------------------------------------------

#define DEVINL __device__ __forceinline__

// block-wide sum over 256 threads (4 waves of 64)
DEVINL float block_sum(float v, float* red) {
#pragma unroll
  for (int off = 32; off > 0; off >>= 1)
    v += __shfl_xor(v, off, 64);
  if ((threadIdx.x & 63) == 0) red[threadIdx.x >> 6] = v;
  __syncthreads();
  float r = red[0] + red[1] + red[2] + red[3];
  __syncthreads();
  return r;
}

// LayerNorm over rows of 1024. One block per row.
__global__ __launch_bounds__(256)
void ln_kernel(const float* __restrict__ in, const float* __restrict__ g,
               const float* __restrict__ b, float* __restrict__ out) {
  __shared__ float red[4];
  const size_t base = (size_t)blockIdx.x * 1024 + threadIdx.x * 4;
  float4 v = *(const float4*)(in + base);
  float s = block_sum(v.x + v.y + v.z + v.w, red);
  float mean = s * (1.0f / 1024.0f);
  float dx = v.x - mean, dy = v.y - mean, dz = v.z - mean, dw = v.w - mean;
  float sq = block_sum(dx * dx + dy * dy + dz * dz + dw * dw, red);
  float rstd = rsqrtf(sq * (1.0f / 1024.0f) + 1e-5f);
  const float4 gv = *(const float4*)(g + threadIdx.x * 4);
  const float4 bv = *(const float4*)(b + threadIdx.x * 4);
  float4 o;
  o.x = dx * rstd * gv.x + bv.x;
  o.y = dy * rstd * gv.y + bv.y;
  o.z = dz * rstd * gv.z + bv.z;
  o.w = dw * rstd * gv.w + bv.w;
  *(float4*)(out + base) = o;
}

// C[M,N] = A[M,K] @ W[N,K]^T (+bias) (+R) (+relu).  EPI: 1=bias 2=residual 4=relu
template <int EPI>
__global__ __launch_bounds__(256)
void gemm_nt(const float* __restrict__ A, const float* __restrict__ W,
             const float* __restrict__ bias, const float* __restrict__ R,
             float* __restrict__ C, int M, int N, int K) {
  __shared__ float As[32][68];  // [k][m], +4 pad
  __shared__ float Ws[32][68];  // [k][n]
  const int tid = threadIdx.x;
  const int tx = tid & 15, ty = tid >> 4;
  const int m0 = blockIdx.y * 64, n0 = blockIdx.x * 64;
  float acc[4][4] = {};
  for (int k0 = 0; k0 < K; k0 += 32) {
#pragma unroll
    for (int i = 0; i < 2; ++i) {
      int slot = tid + 256 * i;           // 0..511
      int r = slot >> 3;                  // 0..63
      int c4 = (slot & 7) * 4;            // 0..28
      float4 a = *(const float4*)(A + (size_t)(m0 + r) * K + k0 + c4);
      As[c4 + 0][r] = a.x; As[c4 + 1][r] = a.y;
      As[c4 + 2][r] = a.z; As[c4 + 3][r] = a.w;
      float4 w = *(const float4*)(W + (size_t)(n0 + r) * K + k0 + c4);
      Ws[c4 + 0][r] = w.x; Ws[c4 + 1][r] = w.y;
      Ws[c4 + 2][r] = w.z; Ws[c4 + 3][r] = w.w;
    }
    __syncthreads();
#pragma unroll
    for (int kk = 0; kk < 32; ++kk) {
      float4 av = *(const float4*)&As[kk][ty * 4];
      float4 wv = *(const float4*)&Ws[kk][tx * 4];
      const float aa[4] = {av.x, av.y, av.z, av.w};
      const float ww[4] = {wv.x, wv.y, wv.z, wv.w};
#pragma unroll
      for (int i = 0; i < 4; ++i)
#pragma unroll
        for (int j = 0; j < 4; ++j)
          acc[i][j] = fmaf(aa[i], ww[j], acc[i][j]);
    }
    __syncthreads();
  }
  const int nb = n0 + tx * 4;
  float4 bv = {0.f, 0.f, 0.f, 0.f};
  if (EPI & 1) bv = *(const float4*)(bias + nb);
#pragma unroll
  for (int i = 0; i < 4; ++i) {
    const int m = m0 + ty * 4 + i;
    float4 o;
    o.x = acc[i][0] + bv.x; o.y = acc[i][1] + bv.y;
    o.z = acc[i][2] + bv.z; o.w = acc[i][3] + bv.w;
    if (EPI & 2) {
      float4 rv = *(const float4*)(R + (size_t)m * N + nb);
      o.x += rv.x; o.y += rv.y; o.z += rv.z; o.w += rv.w;
    }
    if (EPI & 4) {
      o.x = fmaxf(o.x, 0.f); o.y = fmaxf(o.y, 0.f);
      o.z = fmaxf(o.z, 0.f); o.w = fmaxf(o.w, 0.f);
    }
    *(float4*)(C + (size_t)m * N + nb) = o;
  }
}

// Flash-style attention. q/k/v/ctx layout: [B, S, H, 64] (element offset
// head + s*1024 + d with head = (b*S*H + h)*64). Q pre-scaled by 1/sqrt(64).
// grid: x = S/64 query tiles (32), y = B*H (32). 256 threads.
__global__ __launch_bounds__(256)
void attn_kernel(const float* __restrict__ Q, const float* __restrict__ K,
                 const float* __restrict__ V, float* __restrict__ O) {
  __shared__ float Qs[64][68];
  __shared__ float Ks[32][68];
  __shared__ float Vs[32][68];
  __shared__ float Ps[32][68];  // [key][row]
  const int tid = threadIdx.x;
  const int tx = tid & 15, ty = tid >> 4;   // tx: key groups, ty: 4-row group
  const int qt = blockIdx.x;
  const int b = blockIdx.y >> 4, h = blockIdx.y & 15;
  const size_t head = ((size_t)b * 2048 * 16 + h) * 64;

#pragma unroll
  for (int i = 0; i < 4; ++i) {
    int slot = tid + 256 * i;
    int r = slot >> 4, c = (slot & 15) * 4;
    float4 qv = *(const float4*)(Q + head + (size_t)(qt * 64 + r) * 1024 + c);
    qv.x *= 0.125f; qv.y *= 0.125f; qv.z *= 0.125f; qv.w *= 0.125f;
    *(float4*)&Qs[r][c] = qv;
  }
  float mrun[4], lrun[4], acc[4][4];
#pragma unroll
  for (int i = 0; i < 4; ++i) {
    mrun[i] = -1e30f; lrun[i] = 0.f;
#pragma unroll
    for (int j = 0; j < 4; ++j) acc[i][j] = 0.f;
  }

  for (int kt = 0; kt < 64; ++kt) {
    __syncthreads();  // prev PV done (and Q visible on first iter)
#pragma unroll
    for (int i = 0; i < 2; ++i) {
      int slot = tid + 256 * i;
      int r = slot >> 4, c = (slot & 15) * 4;
      *(float4*)&Ks[r][c] =
          *(const float4*)(K + head + (size_t)(kt * 32 + r) * 1024 + c);
      *(float4*)&Vs[r][c] =
          *(const float4*)(V + head + (size_t)(kt * 32 + r) * 1024 + c);
    }
    __syncthreads();

    // scores: rows ty*4+i, keys tx and tx+16
    float sc[4][2] = {};
#pragma unroll
    for (int dd = 0; dd < 64; dd += 4) {
      float4 k0 = *(const float4*)&Ks[tx][dd];
      float4 k1 = *(const float4*)&Ks[tx + 16][dd];
#pragma unroll
      for (int i = 0; i < 4; ++i) {
        float4 qv = *(const float4*)&Qs[ty * 4 + i][dd];
        sc[i][0] += qv.x * k0.x + qv.y * k0.y + qv.z * k0.z + qv.w * k0.w;
        sc[i][1] += qv.x * k1.x + qv.y * k1.y + qv.z * k1.z + qv.w * k1.w;
      }
    }
    // online softmax (row stats reduced over the 16 tx lanes)
    float pj[4][2];
#pragma unroll
    for (int i = 0; i < 4; ++i) {
      float tm = fmaxf(sc[i][0], sc[i][1]);
#pragma unroll
      for (int off = 1; off < 16; off <<= 1)
        tm = fmaxf(tm, __shfl_xor(tm, off, 64));
      float mnew = fmaxf(mrun[i], tm);
      float alpha = __expf(mrun[i] - mnew);
      mrun[i] = mnew;
      float p0 = __expf(sc[i][0] - mnew);
      float p1 = __expf(sc[i][1] - mnew);
      pj[i][0] = p0; pj[i][1] = p1;
      float rs = p0 + p1;
#pragma unroll
      for (int off = 1; off < 16; off <<= 1)
        rs += __shfl_xor(rs, off, 64);
      lrun[i] = lrun[i] * alpha + rs;
#pragma unroll
      for (int j = 0; j < 4; ++j) acc[i][j] *= alpha;
    }
#pragma unroll
    for (int j = 0; j < 2; ++j) {
      float4 pv = {pj[0][j], pj[1][j], pj[2][j], pj[3][j]};
      *(float4*)&Ps[tx + 16 * j][ty * 4] = pv;
    }
    __syncthreads();
    // PV: acc[i][j] += sum_k P[k][row] * V[k][dim]
#pragma unroll
    for (int kk = 0; kk < 32; ++kk) {
      float4 pr = *(const float4*)&Ps[kk][ty * 4];
      float4 vr = *(const float4*)&Vs[kk][tx * 4];
      const float pp[4] = {pr.x, pr.y, pr.z, pr.w};
      const float vv[4] = {vr.x, vr.y, vr.z, vr.w};
#pragma unroll
      for (int i = 0; i < 4; ++i)
#pragma unroll
        for (int j = 0; j < 4; ++j)
          acc[i][j] = fmaf(pp[i], vv[j], acc[i][j]);
    }
  }

#pragma unroll
  for (int i = 0; i < 4; ++i) {
    float inv = 1.0f / lrun[i];
    float4 o = {acc[i][0] * inv, acc[i][1] * inv, acc[i][2] * inv,
                acc[i][3] * inv};
    *(float4*)(O + head + (size_t)(qt * 64 + ty * 4 + i) * 1024 + tx * 4) = o;
  }
}

extern "C" void kernel_launch(void* const* d_in, const int* in_sizes, int n_in,
                              void* d_out, int out_size, void* d_ws,
                              size_t ws_size, hipStream_t stream) {
  const float* x    = (const float*)d_in[0];
  const float* Wq   = (const float*)d_in[1];
  const float* Wk   = (const float*)d_in[2];
  const float* Wv   = (const float*)d_in[3];
  const float* Wo   = (const float*)d_in[4];
  const float* bo   = (const float*)d_in[5];
  const float* ln1g = (const float*)d_in[6];
  const float* ln1b = (const float*)d_in[7];
  const float* W1   = (const float*)d_in[8];
  const float* b1   = (const float*)d_in[9];
  const float* W2   = (const float*)d_in[10];
  const float* b2   = (const float*)d_in[11];
  const float* ln2g = (const float*)d_in[12];
  const float* ln2b = (const float*)d_in[13];
  float* out = (float*)d_out;   // doubles as n1 / layer-input buffer
  float* ws = (float*)d_ws;

  float* t0  = ws;                  // 4M floats (16MB): pre-LN buffer
  float* big = ws + (4u << 20);     // 16M floats (64MB)
  float* q   = big;
  float* k   = big + (4u << 20);
  float* v   = big + (8u << 20);
  float* ctx = big + (12u << 20);
  float* ff  = big;                 // aliases q/k/v/ctx (dead by then)

  const float* cur = x;
  for (int l = 0; l < 3; ++l) {
    // QKV: x viewed as [B*S*H, 64] @ W^T[64,64]
    gemm_nt<0><<<dim3(1, 1024), 256, 0, stream>>>(
        cur, Wq + l * 4096, nullptr, nullptr, q, 65536, 64, 64);
    gemm_nt<0><<<dim3(1, 1024), 256, 0, stream>>>(
        cur, Wk + l * 4096, nullptr, nullptr, k, 65536, 64, 64);
    gemm_nt<0><<<dim3(1, 1024), 256, 0, stream>>>(
        cur, Wv + l * 4096, nullptr, nullptr, v, 65536, 64, 64);
    attn_kernel<<<dim3(32, 32), 256, 0, stream>>>(q, k, v, ctx);
    // att_out = ctx @ Wo^T + bo + residual(cur)
    gemm_nt<3><<<dim3(16, 64), 256, 0, stream>>>(
        ctx, Wo + (size_t)l * 1048576, bo + l * 1024, cur, t0, 4096, 1024, 1024);
    ln_kernel<<<4096, 256, 0, stream>>>(t0, ln1g + l * 1024, ln1b + l * 1024, out);
    // ff1 = relu(n1 @ W1^T + b1)
    gemm_nt<5><<<dim3(64, 64), 256, 0, stream>>>(
        out, W1 + (size_t)l * 4194304, b1 + l * 4096, nullptr, ff, 4096, 4096, 1024);
    // ff2 = ff1 @ W2^T + b2 + n1
    gemm_nt<3><<<dim3(16, 64), 256, 0, stream>>>(
        ff, W2 + (size_t)l * 4194304, b2 + l * 1024, out, t0, 4096, 1024, 4096);
    ln_kernel<<<4096, 256, 0, stream>>>(t0, ln2g + l * 1024, ln2b + l * 1024, out);
    cur = out;
  }
}

// Round 2
// 1722.372 us; speedup vs baseline: 3.3974x; 3.3974x over previous
//
#include <hip/hip_runtime.h>
#include <math.h>

// ---------------------------------------------------------------------------
// TransformerEncoder L=3,B=2,S=2048,D=1024,H=16,Dh=64,DF=4096.
// Round 2: bf16 MFMA everywhere (fp32 accum). fp32 LN/residual glue.
// ---------------------------------------------------------------------------

#define DEVINL __device__ __forceinline__
typedef unsigned short ushort_t;
using short8 = __attribute__((ext_vector_type(8))) short;
using f32x4  = __attribute__((ext_vector_type(4))) float;

DEVINL short f2b(float f) {  // fp32 -> bf16 bits, RNE
  unsigned u = __float_as_uint(f);
  u += 0x7fff + ((u >> 16) & 1);
  return (short)(u >> 16);
}
DEVINL f32x4 mfma16(short8 a, short8 b, f32x4 c) {
  return __builtin_amdgcn_mfma_f32_16x16x32_bf16(a, b, c, 0, 0, 0);
}

// --------------------------- LayerNorm (fp32) ------------------------------
DEVINL float block_sum(float v, float* red) {
#pragma unroll
  for (int off = 32; off > 0; off >>= 1) v += __shfl_xor(v, off, 64);
  if ((threadIdx.x & 63) == 0) red[threadIdx.x >> 6] = v;
  __syncthreads();
  float r = red[0] + red[1] + red[2] + red[3];
  __syncthreads();
  return r;
}

__global__ __launch_bounds__(256)
void ln_kernel(const float* __restrict__ in, const float* __restrict__ g,
               const float* __restrict__ b, float* __restrict__ out) {
  __shared__ float red[4];
  const size_t base = (size_t)blockIdx.x * 1024 + threadIdx.x * 4;
  float4 v = *(const float4*)(in + base);
  float s = block_sum(v.x + v.y + v.z + v.w, red);
  float mean = s * (1.0f / 1024.0f);
  float dx = v.x - mean, dy = v.y - mean, dz = v.z - mean, dw = v.w - mean;
  float sq = block_sum(dx * dx + dy * dy + dz * dz + dw * dw, red);
  float rstd = rsqrtf(sq * (1.0f / 1024.0f) + 1e-5f);
  const float4 gv = *(const float4*)(g + threadIdx.x * 4);
  const float4 bv = *(const float4*)(b + threadIdx.x * 4);
  float4 o;
  o.x = dx * rstd * gv.x + bv.x;
  o.y = dy * rstd * gv.y + bv.y;
  o.z = dz * rstd * gv.z + bv.z;
  o.w = dw * rstd * gv.w + bv.w;
  *(float4*)(out + base) = o;
}

// --------------------------- MFMA GEMM -------------------------------------
// C[M,N] = A[M,K] @ W[N,K]^T (+bias)(+R fp32)(+relu).
// A: fp32 or bf16 (ABF). W: fp32. C: fp32 or bf16 (OBF).
// BK=64. LDS XOR-swizzled (kg ^= row&7). 4 waves in 2x2 layout.
template <int BM, int BN, bool ABF, bool OBF, int EPI>
__global__ __launch_bounds__(256)
void gemm_mfma(const void* __restrict__ Ap, const float* __restrict__ W,
               const float* __restrict__ bias, const float* __restrict__ R,
               void* __restrict__ Cp, int M, int N, int K) {
  constexpr int FM = BM / 32;
  constexpr int FN = BN / 32;
  constexpr int CA = (BM * 8) / 256;  // 8-elem chunks per thread for A
  constexpr int CB = (BN * 8) / 256;
  __shared__ __align__(16) short As[BM * 64];
  __shared__ __align__(16) short Bs[BN * 64];
  const int tid = threadIdx.x;
  const int lane = tid & 63, lo = lane & 15, hi = lane >> 4, w = tid >> 6;
  const int m0 = blockIdx.y * BM, n0 = blockIdx.x * BN;
  const int wm = (w >> 1) * (BM / 2), wn = (w & 1) * (BN / 2);

  f32x4 acc[FM][FN] = {};

  for (int k0 = 0; k0 < K; k0 += 64) {
    // stage A
#pragma unroll
    for (int i = 0; i < CA; ++i) {
      int c = tid + i * 256;
      int row = c >> 3, kg = c & 7;
      short8 hv;
      if (ABF) {
        hv = *(const short8*)((const ushort_t*)Ap + (size_t)(m0 + row) * K +
                              k0 + kg * 8);
      } else {
        const float* src = (const float*)Ap + (size_t)(m0 + row) * K + k0 + kg * 8;
        float4 f0 = *(const float4*)src;
        float4 f1 = *(const float4*)(src + 4);
        hv[0] = f2b(f0.x); hv[1] = f2b(f0.y); hv[2] = f2b(f0.z); hv[3] = f2b(f0.w);
        hv[4] = f2b(f1.x); hv[5] = f2b(f1.y); hv[6] = f2b(f1.z); hv[7] = f2b(f1.w);
      }
      *(short8*)&As[row * 64 + ((kg ^ (row & 7)) << 3)] = hv;
    }
    // stage B (weights, fp32)
#pragma unroll
    for (int i = 0; i < CB; ++i) {
      int c = tid + i * 256;
      int row = c >> 3, kg = c & 7;
      const float* src = W + (size_t)(n0 + row) * K + k0 + kg * 8;
      float4 f0 = *(const float4*)src;
      float4 f1 = *(const float4*)(src + 4);
      short8 hv;
      hv[0] = f2b(f0.x); hv[1] = f2b(f0.y); hv[2] = f2b(f0.z); hv[3] = f2b(f0.w);
      hv[4] = f2b(f1.x); hv[5] = f2b(f1.y); hv[6] = f2b(f1.z); hv[7] = f2b(f1.w);
      *(short8*)&Bs[row * 64 + ((kg ^ (row & 7)) << 3)] = hv;
    }
    __syncthreads();
#pragma unroll
    for (int ks = 0; ks < 2; ++ks) {
      short8 af[FM], bf[FN];
#pragma unroll
      for (int fm = 0; fm < FM; ++fm) {
        int row = wm + fm * 16 + lo;
        int kg = ks * 4 + hi;
        af[fm] = *(const short8*)&As[row * 64 + ((kg ^ (row & 7)) << 3)];
      }
#pragma unroll
      for (int fn = 0; fn < FN; ++fn) {
        int row = wn + fn * 16 + lo;
        int kg = ks * 4 + hi;
        bf[fn] = *(const short8*)&Bs[row * 64 + ((kg ^ (row & 7)) << 3)];
      }
#pragma unroll
      for (int fm = 0; fm < FM; ++fm)
#pragma unroll
        for (int fn = 0; fn < FN; ++fn)
          acc[fm][fn] = mfma16(af[fm], bf[fn], acc[fm][fn]);
    }
    __syncthreads();
  }

  // epilogue
  float bv[FN];
#pragma unroll
  for (int fn = 0; fn < FN; ++fn)
    bv[fn] = (EPI & 1) ? bias[n0 + wn + fn * 16 + lo] : 0.f;
#pragma unroll
  for (int fm = 0; fm < FM; ++fm)
#pragma unroll
    for (int fn = 0; fn < FN; ++fn) {
      const int col = n0 + wn + fn * 16 + lo;
#pragma unroll
      for (int r = 0; r < 4; ++r) {
        const int row = m0 + wm + fm * 16 + hi * 4 + r;
        float v = acc[fm][fn][r] + bv[fn];
        if (EPI & 2) v += R[(size_t)row * N + col];
        if (EPI & 4) v = fmaxf(v, 0.f);
        if (OBF)
          ((ushort_t*)Cp)[(size_t)row * N + col] = (ushort_t)f2b(v);
        else
          ((float*)Cp)[(size_t)row * N + col] = v;
      }
    }
}

// --------------------------- V transpose -----------------------------------
// V [B,S,HD=1024] bf16 -> VT [B,HD,S] bf16.  grid (S/64, HD/64, B), 256 thr.
__global__ __launch_bounds__(256)
void vtrans(const ushort_t* __restrict__ V, ushort_t* __restrict__ VT) {
  __shared__ ushort_t T[64][65];
  const int tid = threadIdx.x;
  const int s0 = blockIdx.x * 64, hd0 = blockIdx.y * 64, b = blockIdx.z;
  const ushort_t* src = V + (size_t)b * 2097152;
  ushort_t* dst = VT + (size_t)b * 2097152;
#pragma unroll
  for (int i = 0; i < 2; ++i) {
    int c = tid + i * 256;
    int s = c >> 3, kg = c & 7;
    short8 hv = *(const short8*)(src + (size_t)(s0 + s) * 1024 + hd0 + kg * 8);
#pragma unroll
    for (int j = 0; j < 8; ++j) T[s][kg * 8 + j] = (ushort_t)hv[j];
  }
  __syncthreads();
#pragma unroll
  for (int i = 0; i < 2; ++i) {
    int c = tid + i * 256;
    int hd = c >> 3, sg = c & 7;
    short8 o;
#pragma unroll
    for (int j = 0; j < 8; ++j) o[j] = (short)T[sg * 8 + j][hd];
    *(short8*)(dst + (size_t)(hd0 + hd) * 2048 + s0 + sg * 8) = o;
  }
}

// --------------------------- MFMA flash attention --------------------------
// Q,K layout [B,S,H,64] bf16; VT layout [B,H*64,S] bf16; O [B,S,H,64] bf16.
// grid (S/64, B*H), 256 thr; wave w handles 16 q-rows. Scores scaled 0.125.
__global__ __launch_bounds__(256)
void attn_mfma(const ushort_t* __restrict__ Q, const ushort_t* __restrict__ Kb,
               const ushort_t* __restrict__ VT, ushort_t* __restrict__ O) {
  __shared__ __align__(16) short Pl[4096];  // 4 waves x [16q][64key] swizzled
  const int tid = threadIdx.x;
  const int w = tid >> 6, lane = tid & 63, lo = lane & 15, hi = lane >> 4;
  const int qt = blockIdx.x, b = blockIdx.y >> 4, h = blockIdx.y & 15;
  const size_t head = (size_t)b * 2097152 + (size_t)h * 64;
  const size_t vth = (size_t)b * 2097152 + (size_t)h * 131072;
  const int qrow = qt * 64 + w * 16;
  short* P = Pl + w * 1024;

  short8 qf[2];
  qf[0] = *(const short8*)(Q + head + (size_t)(qrow + lo) * 1024 + hi * 8);
  qf[1] = *(const short8*)(Q + head + (size_t)(qrow + lo) * 1024 + 32 + hi * 8);

  f32x4 acc[4] = {};
  float m[4], lsum[4];
#pragma unroll
  for (int r = 0; r < 4; ++r) { m[r] = -1e30f; lsum[r] = 0.f; }

  for (int kt = 0; kt < 32; ++kt) {
    f32x4 sc[4] = {};
    const ushort_t* kbase = Kb + head + (size_t)(kt * 64) * 1024;
#pragma unroll
    for (int fm = 0; fm < 4; ++fm) {
      const ushort_t* kr = kbase + (size_t)(fm * 16 + lo) * 1024 + hi * 8;
      sc[fm] = mfma16(qf[0], *(const short8*)kr, sc[fm]);
      sc[fm] = mfma16(qf[1], *(const short8*)(kr + 32), sc[fm]);
    }
#pragma unroll
    for (int fm = 0; fm < 4; ++fm) sc[fm] *= 0.125f;

#pragma unroll
    for (int r = 0; r < 4; ++r) {
      float tm = fmaxf(fmaxf(sc[0][r], sc[1][r]), fmaxf(sc[2][r], sc[3][r]));
      tm = fmaxf(tm, __shfl_xor(tm, 1));
      tm = fmaxf(tm, __shfl_xor(tm, 2));
      tm = fmaxf(tm, __shfl_xor(tm, 4));
      tm = fmaxf(tm, __shfl_xor(tm, 8));
      float mn = fmaxf(m[r], tm);
      float al = __expf(m[r] - mn);
      m[r] = mn;
      float rs = 0.f;
#pragma unroll
      for (int fm = 0; fm < 4; ++fm) {
        float p = __expf(sc[fm][r] - mn);
        sc[fm][r] = p;
        rs += p;
      }
      rs += __shfl_xor(rs, 1);
      rs += __shfl_xor(rs, 2);
      rs += __shfl_xor(rs, 4);
      rs += __shfl_xor(rs, 8);
      lsum[r] = lsum[r] * al + rs;
#pragma unroll
      for (int fn = 0; fn < 4; ++fn) acc[fn][r] *= al;
    }
    // write P (bf16) to swizzled per-wave LDS: element (q, key)
#pragma unroll
    for (int fm = 0; fm < 4; ++fm) {
      const int key = fm * 16 + lo;
#pragma unroll
      for (int r = 0; r < 4; ++r) {
        const int q = hi * 4 + r;
        P[q * 64 + ((((key >> 3) ^ (q & 7)) << 3) | (key & 7))] =
            f2b(sc[fm][r]);
      }
    }
    // PV
#pragma unroll
    for (int ks = 0; ks < 2; ++ks) {
      short8 pa =
          *(const short8*)&P[lo * 64 + (((ks * 4 + hi) ^ (lo & 7)) << 3)];
      const ushort_t* vb = VT + vth + (size_t)kt * 64 + ks * 32 + hi * 8;
#pragma unroll
      for (int fn = 0; fn < 4; ++fn)
        acc[fn] = mfma16(pa, *(const short8*)(vb + (size_t)(fn * 16 + lo) * 2048),
                         acc[fn]);
    }
  }

#pragma unroll
  for (int r = 0; r < 4; ++r) {
    const float inv = 1.0f / lsum[r];
    const size_t rb = head + (size_t)(qrow + hi * 4 + r) * 1024;
#pragma unroll
    for (int fn = 0; fn < 4; ++fn)
      O[rb + fn * 16 + lo] = (ushort_t)f2b(acc[fn][r] * inv);
  }
}

// --------------------------- launcher --------------------------------------
extern "C" void kernel_launch(void* const* d_in, const int* in_sizes, int n_in,
                              void* d_out, int out_size, void* d_ws,
                              size_t ws_size, hipStream_t stream) {
  const float* x    = (const float*)d_in[0];
  const float* Wq   = (const float*)d_in[1];
  const float* Wk   = (const float*)d_in[2];
  const float* Wv   = (const float*)d_in[3];
  const float* Wo   = (const float*)d_in[4];
  const float* bo   = (const float*)d_in[5];
  const float* ln1g = (const float*)d_in[6];
  const float* ln1b = (const float*)d_in[7];
  const float* W1   = (const float*)d_in[8];
  const float* b1   = (const float*)d_in[9];
  const float* W2   = (const float*)d_in[10];
  const float* b2   = (const float*)d_in[11];
  const float* ln2g = (const float*)d_in[12];
  const float* ln2b = (const float*)d_in[13];
  float* out = (float*)d_out;
  char* wsb = (char*)d_ws;

  float*    t0  = (float*)wsb;                          // 16 MB fp32
  ushort_t* q   = (ushort_t*)(wsb + (16u << 20));       // 8 MB bf16
  ushort_t* k   = (ushort_t*)(wsb + (24u << 20));
  ushort_t* v   = (ushort_t*)(wsb + (32u << 20));
  ushort_t* vt  = (ushort_t*)(wsb + (40u << 20));
  ushort_t* ctx = (ushort_t*)(wsb + (48u << 20));
  ushort_t* ff  = q;  // 32 MB alias over q/k/v/vt (dead after attention)

  const float* cur = x;
  for (int l = 0; l < 3; ++l) {
    // QKV: [65536,64] = A[65536,64](fp32) @ W[64,64]^T -> bf16
    gemm_mfma<128, 64, false, true, 0><<<dim3(1, 512), 256, 0, stream>>>(
        cur, Wq + l * 4096, nullptr, nullptr, q, 65536, 64, 64);
    gemm_mfma<128, 64, false, true, 0><<<dim3(1, 512), 256, 0, stream>>>(
        cur, Wk + l * 4096, nullptr, nullptr, k, 65536, 64, 64);
    gemm_mfma<128, 64, false, true, 0><<<dim3(1, 512), 256, 0, stream>>>(
        cur, Wv + l * 4096, nullptr, nullptr, v, 65536, 64, 64);
    vtrans<<<dim3(32, 16, 2), 256, 0, stream>>>(v, vt);
    attn_mfma<<<dim3(32, 32), 256, 0, stream>>>(q, k, vt, ctx);
    // att_out = ctx @ Wo^T + bo + cur -> t0 (fp32)
    gemm_mfma<64, 128, true, false, 3><<<dim3(8, 64), 256, 0, stream>>>(
        ctx, Wo + (size_t)l * 1048576, bo + l * 1024, cur, t0, 4096, 1024, 1024);
    ln_kernel<<<4096, 256, 0, stream>>>(t0, ln1g + l * 1024, ln1b + l * 1024, out);
    // ff1 = relu(n1 @ W1^T + b1) -> bf16
    gemm_mfma<128, 128, false, true, 5><<<dim3(32, 32), 256, 0, stream>>>(
        out, W1 + (size_t)l * 4194304, b1 + l * 4096, nullptr, ff, 4096, 4096, 1024);
    // ff2 = ff1 @ W2^T + b2 + n1 -> t0 (fp32)
    gemm_mfma<64, 128, true, false, 3><<<dim3(8, 64), 256, 0, stream>>>(
        ff, W2 + (size_t)l * 4194304, b2 + l * 1024, out, t0, 4096, 1024, 4096);
    ln_kernel<<<4096, 256, 0, stream>>>(t0, ln2g + l * 1024, ln2b + l * 1024, out);
    cur = out;
  }
}

// Round 3
// 1284.824 us; speedup vs baseline: 4.5544x; 1.3406x over previous
//
#include <hip/hip_runtime.h>
#include <math.h>

// ---------------------------------------------------------------------------
// TransformerEncoder L=3,B=2,S=2048,D=1024,H=16,Dh=64,DF=4096.
// Round 3: bf16 weights pre-converted; m97-style GEMM (global_load_lds w16,
// linear LDS, 2-barrier); latency-optimized attention (swapped QK, no-max
// softmax, K-prefetch, packed P).
// ---------------------------------------------------------------------------

#define DEVINL __device__ __forceinline__
typedef unsigned short ushort_t;
using short8 = __attribute__((ext_vector_type(8))) short;
using f32x4  = __attribute__((ext_vector_type(4))) float;

DEVINL short f2b(float f) {  // fp32 -> bf16 bits, RNE
  unsigned u = __float_as_uint(f);
  u += 0x7fff + ((u >> 16) & 1);
  return (short)(u >> 16);
}
DEVINL unsigned pk2(float a, float b) {  // two fp32 -> packed bf16x2
  unsigned ua = __float_as_uint(a), ub = __float_as_uint(b);
  ua += 0x7fff + ((ua >> 16) & 1);
  ub += 0x7fff + ((ub >> 16) & 1);
  return (ua >> 16) | (ub & 0xffff0000u);
}
DEVINL f32x4 mfma16(short8 a, short8 b, f32x4 c) {
  return __builtin_amdgcn_mfma_f32_16x16x32_bf16(a, b, c, 0, 0, 0);
}

typedef __attribute__((address_space(3))) void lds_void;
typedef __attribute__((address_space(1))) void gbl_void;
DEVINL void gl16(const void* g, void* l) {
  // global -> LDS direct copy, 16B per lane. LDS dest must be linear
  // (wave-uniform base + lane*16).
  __builtin_amdgcn_global_load_lds((const gbl_void*)(unsigned long long)g,
                                   (lds_void*)(unsigned long long)l, 16, 0, 0);
}

// --------------------------- fp32 -> bf16 convert ---------------------------
__global__ __launch_bounds__(256)
void conv_bf16(const float* __restrict__ src, ushort_t* __restrict__ dst,
               int n8) {
  int i = blockIdx.x * 256 + threadIdx.x;
  const int stride = gridDim.x * 256;
  for (; i < n8; i += stride) {
    float4 a = ((const float4*)src)[2 * i];
    float4 b = ((const float4*)src)[2 * i + 1];
    uint4 o;
    o.x = pk2(a.x, a.y); o.y = pk2(a.z, a.w);
    o.z = pk2(b.x, b.y); o.w = pk2(b.z, b.w);
    ((uint4*)dst)[i] = o;
  }
}

// --------------------------- LayerNorm (fp32 + bf16 out) --------------------
DEVINL float block_sum(float v, float* red) {
#pragma unroll
  for (int off = 32; off > 0; off >>= 1) v += __shfl_xor(v, off, 64);
  if ((threadIdx.x & 63) == 0) red[threadIdx.x >> 6] = v;
  __syncthreads();
  float r = red[0] + red[1] + red[2] + red[3];
  __syncthreads();
  return r;
}

__global__ __launch_bounds__(256)
void ln_dual(const float* __restrict__ in, const float* __restrict__ g,
             const float* __restrict__ b, float* __restrict__ outf,
             ushort_t* __restrict__ outb) {
  __shared__ float red[4];
  const size_t base = (size_t)blockIdx.x * 1024 + threadIdx.x * 4;
  float4 v = *(const float4*)(in + base);
  float s = block_sum(v.x + v.y + v.z + v.w, red);
  float mean = s * (1.0f / 1024.0f);
  float dx = v.x - mean, dy = v.y - mean, dz = v.z - mean, dw = v.w - mean;
  float sq = block_sum(dx * dx + dy * dy + dz * dz + dw * dw, red);
  float rstd = rsqrtf(sq * (1.0f / 1024.0f) + 1e-5f);
  const float4 gv = *(const float4*)(g + threadIdx.x * 4);
  const float4 bv = *(const float4*)(b + threadIdx.x * 4);
  float4 o;
  o.x = dx * rstd * gv.x + bv.x;
  o.y = dy * rstd * gv.y + bv.y;
  o.z = dz * rstd * gv.z + bv.z;
  o.w = dw * rstd * gv.w + bv.w;
  *(float4*)(outf + base) = o;
  uint2 p;
  p.x = pk2(o.x, o.y); p.y = pk2(o.z, o.w);
  *(uint2*)(outb + base) = p;
}

// --------------------------- MFMA GEMM (all-bf16 in) ------------------------
// C[M,N] = A[M,K] @ W[N,K]^T (+bias)(+R fp32)(+relu). EPI:1=bias 2=res 4=relu
// m97 structure: global_load_lds w16 -> linear LDS, 2 barriers per K-step.
template <int BM, int BN, bool OBF, int EPI, bool SWZ>
__global__ __launch_bounds__(256)
void gemm_bf16(const ushort_t* __restrict__ A, const ushort_t* __restrict__ W,
               const float* __restrict__ bias, const float* __restrict__ R,
               void* __restrict__ Cp, int M, int N, int K) {
  constexpr int FM = BM / 32;
  constexpr int FN = BN / 32;
  __shared__ __align__(16) ushort_t As[BM * 64];
  __shared__ __align__(16) ushort_t Bs[BN * 64];
  const int tid = threadIdx.x;
  const int lane = tid & 63, lo = lane & 15, hi = lane >> 4, w = tid >> 6;
  int bx = blockIdx.x, by = blockIdx.y;
  if (SWZ) {  // XCD-aware swizzle (nwg % 8 == 0 for all our launches)
    int id = by * gridDim.x + bx;
    const int cpx = (gridDim.x * gridDim.y) >> 3;
    id = (id & 7) * cpx + (id >> 3);
    bx = id % gridDim.x;
    by = id / gridDim.x;
  }
  const int m0 = by * BM, n0 = bx * BN;
  const int wm = (w >> 1) * (BM / 2), wn = (w & 1) * (BN / 2);

  f32x4 acc[FM][FN] = {};

  for (int k0 = 0; k0 < K; k0 += 64) {
#pragma unroll
    for (int i = 0; i < BM * 8 / 256; ++i) {
      const int c = i * 256 + tid;
      gl16(A + (size_t)(m0 + (c >> 3)) * K + k0 + (c & 7) * 8, As + c * 8);
    }
#pragma unroll
    for (int i = 0; i < BN * 8 / 256; ++i) {
      const int c = i * 256 + tid;
      gl16(W + (size_t)(n0 + (c >> 3)) * K + k0 + (c & 7) * 8, Bs + c * 8);
    }
    __syncthreads();  // drains vmcnt(0) -> LDS valid
#pragma unroll
    for (int ks = 0; ks < 2; ++ks) {
      short8 af[FM], bf[FN];
#pragma unroll
      for (int fm = 0; fm < FM; ++fm)
        af[fm] = *(const short8*)&As[(wm + fm * 16 + lo) * 64 + ks * 32 + hi * 8];
#pragma unroll
      for (int fn = 0; fn < FN; ++fn)
        bf[fn] = *(const short8*)&Bs[(wn + fn * 16 + lo) * 64 + ks * 32 + hi * 8];
#pragma unroll
      for (int fm = 0; fm < FM; ++fm)
#pragma unroll
        for (int fn = 0; fn < FN; ++fn)
          acc[fm][fn] = mfma16(af[fm], bf[fn], acc[fm][fn]);
    }
    __syncthreads();
  }

  float bv[FN];
#pragma unroll
  for (int fn = 0; fn < FN; ++fn)
    bv[fn] = (EPI & 1) ? bias[n0 + wn + fn * 16 + lo] : 0.f;
#pragma unroll
  for (int fm = 0; fm < FM; ++fm)
#pragma unroll
    for (int fn = 0; fn < FN; ++fn) {
      const int col = n0 + wn + fn * 16 + lo;
#pragma unroll
      for (int r = 0; r < 4; ++r) {
        const int row = m0 + wm + fm * 16 + hi * 4 + r;
        float v = acc[fm][fn][r] + bv[fn];
        if (EPI & 2) v += R[(size_t)row * N + col];
        if (EPI & 4) v = fmaxf(v, 0.f);
        if (OBF)
          ((ushort_t*)Cp)[(size_t)row * N + col] = (ushort_t)f2b(v);
        else
          ((float*)Cp)[(size_t)row * N + col] = v;
      }
    }
}

// --------------------------- fused QKV ------------------------------------
// A[65536,64] bf16 (rows = (b,s,h)); q = 0.125 * A@Wq^T, k = A@Wk^T, v = A@Wv^T
__global__ __launch_bounds__(256)
void qkv_kernel(const ushort_t* __restrict__ A, const ushort_t* __restrict__ Wq,
                const ushort_t* __restrict__ Wk, const ushort_t* __restrict__ Wv,
                ushort_t* __restrict__ q, ushort_t* __restrict__ k,
                ushort_t* __restrict__ v) {
  __shared__ __align__(16) ushort_t As[128 * 64];
  __shared__ __align__(16) ushort_t Ws[3][64 * 64];
  const int tid = threadIdx.x;
  const int lane = tid & 63, lo = lane & 15, hi = lane >> 4, w = tid >> 6;
  const int m0 = blockIdx.x * 128;
  const int wm = (w >> 1) * 64, wn = (w & 1) * 32;

#pragma unroll
  for (int i = 0; i < 4; ++i) {
    const int c = i * 256 + tid;
    gl16(A + (size_t)(m0 + (c >> 3)) * 64 + (c & 7) * 8, As + c * 8);
  }
#pragma unroll
  for (int o = 0; o < 3; ++o) {
    const ushort_t* wb = (o == 0) ? Wq : (o == 1) ? Wk : Wv;
#pragma unroll
    for (int i = 0; i < 2; ++i) {
      const int c = i * 256 + tid;
      gl16(wb + (size_t)(c >> 3) * 64 + (c & 7) * 8, Ws[o] + c * 8);
    }
  }
  __syncthreads();

#pragma unroll
  for (int o = 0; o < 3; ++o) {
    ushort_t* ob = (o == 0) ? q : (o == 1) ? k : v;
    const float sc = (o == 0) ? 0.125f : 1.0f;
    f32x4 acc[4][2] = {};
#pragma unroll
    for (int ks = 0; ks < 2; ++ks) {
      short8 af[4], bf[2];
#pragma unroll
      for (int fm = 0; fm < 4; ++fm)
        af[fm] = *(const short8*)&As[(wm + fm * 16 + lo) * 64 + ks * 32 + hi * 8];
#pragma unroll
      for (int fn = 0; fn < 2; ++fn)
        bf[fn] = *(const short8*)&Ws[o][(wn + fn * 16 + lo) * 64 + ks * 32 + hi * 8];
#pragma unroll
      for (int fm = 0; fm < 4; ++fm)
#pragma unroll
        for (int fn = 0; fn < 2; ++fn)
          acc[fm][fn] = mfma16(af[fm], bf[fn], acc[fm][fn]);
    }
#pragma unroll
    for (int fm = 0; fm < 4; ++fm)
#pragma unroll
      for (int fn = 0; fn < 2; ++fn) {
        const int col = wn + fn * 16 + lo;
#pragma unroll
        for (int r = 0; r < 4; ++r) {
          const int row = m0 + wm + fm * 16 + hi * 4 + r;
          ob[(size_t)row * 64 + col] = (ushort_t)f2b(acc[fm][fn][r] * sc);
        }
      }
  }
}

// --------------------------- V transpose (bf16) -----------------------------
// V [B,S,1024] -> VT [B,1024,S]. grid (S/64, 16, B), 256 thr.
__global__ __launch_bounds__(256)
void vtrans(const ushort_t* __restrict__ V, ushort_t* __restrict__ VT) {
  __shared__ ushort_t T[64][65];
  const int tid = threadIdx.x;
  const int s0 = blockIdx.x * 64, hd0 = blockIdx.y * 64, b = blockIdx.z;
  const ushort_t* src = V + (size_t)b * 2097152;
  ushort_t* dst = VT + (size_t)b * 2097152;
#pragma unroll
  for (int i = 0; i < 2; ++i) {
    int c = tid + i * 256;
    int s = c >> 3, kg = c & 7;
    short8 hv = *(const short8*)(src + (size_t)(s0 + s) * 1024 + hd0 + kg * 8);
#pragma unroll
    for (int j = 0; j < 8; ++j) T[s][kg * 8 + j] = (ushort_t)hv[j];
  }
  __syncthreads();
#pragma unroll
  for (int i = 0; i < 2; ++i) {
    int c = tid + i * 256;
    int hd = c >> 3, sg = c & 7;
    short8 o;
#pragma unroll
    for (int j = 0; j < 8; ++j) o[j] = (short)T[sg * 8 + j][hd];
    *(short8*)(dst + (size_t)(hd0 + hd) * 2048 + s0 + sg * 8) = o;
  }
}

// --------------------------- attention -------------------------------------
// Q,K,O layout [B,S,H,64] bf16 (Q pre-scaled by 0.125); VT [B,H*64,S] bf16.
// Swapped QK^T -> lane owns one q-row; no-max softmax (scores bounded);
// K register-double-buffered; per-wave P in LDS (conflict-free at 64B rows).
__global__ __launch_bounds__(256)
void attn2(const ushort_t* __restrict__ Q, const ushort_t* __restrict__ Kb,
           const ushort_t* __restrict__ VT, ushort_t* __restrict__ O) {
  __shared__ __align__(16) short P[4][16 * 32];
  const int tid = threadIdx.x, w = tid >> 6, lane = tid & 63;
  const int lo = lane & 15, hi = lane >> 4;
  const int b = blockIdx.y >> 4, h = blockIdx.y & 15;
  const size_t head = (size_t)b * 2097152 + (size_t)h * 64;
  const size_t vth = (size_t)b * 2097152 + (size_t)h * 131072;
  const int qrow = blockIdx.x * 64 + w * 16;
  short* Pw = P[w];

  const ushort_t* qp = Q + head + (size_t)(qrow + lo) * 1024 + hi * 8;
  const short8 qf0 = *(const short8*)qp;
  const short8 qf1 = *(const short8*)(qp + 32);

  const ushort_t* kp = Kb + head + (size_t)lo * 1024 + hi * 8;
  const ushort_t* vp = VT + vth + (size_t)lo * 2048 + hi * 8;

  f32x4 acc0 = {}, acc1 = {}, acc2 = {}, acc3 = {};
  float lsum = 0.f;

  short8 ka[4], kb2[4];
#pragma unroll
  for (int fm = 0; fm < 2; ++fm)
#pragma unroll
    for (int ks = 0; ks < 2; ++ks)
      ka[fm * 2 + ks] = *(const short8*)(kp + (size_t)fm * 16384 + ks * 32);

  auto step = [&](int kt, short8* kc, short8* kn) {
    if (kt + 1 < 64) {  // prefetch next K tile into the other reg buffer
      const ushort_t* kpn = kp + (size_t)(kt + 1) * 32768;
#pragma unroll
      for (int fm = 0; fm < 2; ++fm)
#pragma unroll
        for (int ks = 0; ks < 2; ++ks)
          kn[fm * 2 + ks] =
              *(const short8*)(kpn + (size_t)fm * 16384 + ks * 32);
    }
    // QK^T swapped: sc[key 16-group][r] , col = q = lo
    f32x4 sc0 = {}, sc1 = {};
    sc0 = mfma16(kc[0], qf0, sc0);
    sc0 = mfma16(kc[1], qf1, sc0);
    sc1 = mfma16(kc[2], qf0, sc1);
    sc1 = mfma16(kc[3], qf1, sc1);
    // V fragments issued early; softmax covers their latency
    const ushort_t* vpn = vp + kt * 32;
    short8 vf0 = *(const short8*)(vpn);
    short8 vf1 = *(const short8*)(vpn + 32768);
    short8 vf2 = *(const short8*)(vpn + 65536);
    short8 vf3 = *(const short8*)(vpn + 98304);
    // no-max softmax: P = exp(s) (scores bounded; exact softmax after /lsum)
    float p0 = __expf(sc0[0]), p1 = __expf(sc0[1]);
    float p2 = __expf(sc0[2]), p3 = __expf(sc0[3]);
    float p4 = __expf(sc1[0]), p5 = __expf(sc1[1]);
    float p6 = __expf(sc1[2]), p7 = __expf(sc1[3]);
    lsum += ((p0 + p1) + (p2 + p3)) + ((p4 + p5) + (p6 + p7));
    uint2 w0, w1;
    w0.x = pk2(p0, p1); w0.y = pk2(p2, p3);
    w1.x = pk2(p4, p5); w1.y = pk2(p6, p7);
    *(uint2*)&Pw[lo * 32 + hi * 4] = w0;       // keys hi*4..hi*4+3
    *(uint2*)&Pw[lo * 32 + 16 + hi * 4] = w1;  // keys 16+...
    short8 pb = *(const short8*)&Pw[lo * 32 + hi * 8];  // P[q=lo][hi*8..+7]
    acc0 = mfma16(vf0, pb, acc0);
    acc1 = mfma16(vf1, pb, acc1);
    acc2 = mfma16(vf2, pb, acc2);
    acc3 = mfma16(vf3, pb, acc3);
  };
  for (int kt = 0; kt < 64; kt += 2) {
    step(kt, ka, kb2);
    step(kt + 1, kb2, ka);
  }

  lsum += __shfl_xor(lsum, 16);
  lsum += __shfl_xor(lsum, 32);
  const float inv = 1.0f / lsum;
  ushort_t* op = O + head + (size_t)(qrow + lo) * 1024 + hi * 4;
  uint2 o0, o1, o2, o3;
  o0.x = pk2(acc0[0] * inv, acc0[1] * inv);
  o0.y = pk2(acc0[2] * inv, acc0[3] * inv);
  o1.x = pk2(acc1[0] * inv, acc1[1] * inv);
  o1.y = pk2(acc1[2] * inv, acc1[3] * inv);
  o2.x = pk2(acc2[0] * inv, acc2[1] * inv);
  o2.y = pk2(acc2[2] * inv, acc2[3] * inv);
  o3.x = pk2(acc3[0] * inv, acc3[1] * inv);
  o3.y = pk2(acc3[2] * inv, acc3[3] * inv);
  *(uint2*)(op) = o0;
  *(uint2*)(op + 16) = o1;
  *(uint2*)(op + 32) = o2;
  *(uint2*)(op + 48) = o3;
}

// --------------------------- launcher --------------------------------------
extern "C" void kernel_launch(void* const* d_in, const int* in_sizes, int n_in,
                              void* d_out, int out_size, void* d_ws,
                              size_t ws_size, hipStream_t stream) {
  const float* x    = (const float*)d_in[0];
  const float* Wq   = (const float*)d_in[1];
  const float* Wk   = (const float*)d_in[2];
  const float* Wv   = (const float*)d_in[3];
  const float* Wo   = (const float*)d_in[4];
  const float* bo   = (const float*)d_in[5];
  const float* ln1g = (const float*)d_in[6];
  const float* ln1b = (const float*)d_in[7];
  const float* W1   = (const float*)d_in[8];
  const float* b1   = (const float*)d_in[9];
  const float* W2   = (const float*)d_in[10];
  const float* b2   = (const float*)d_in[11];
  const float* ln2g = (const float*)d_in[12];
  const float* ln2b = (const float*)d_in[13];
  float* out = (float*)d_out;
  char* wsb = (char*)d_ws;

  float*    t0  = (float*)wsb;                           // 16 MB fp32
  ushort_t* q   = (ushort_t*)(wsb + (16ull << 20));      // 8 MB each
  ushort_t* k   = (ushort_t*)(wsb + (24ull << 20));
  ushort_t* v   = (ushort_t*)(wsb + (32ull << 20));
  ushort_t* vt  = (ushort_t*)(wsb + (40ull << 20));
  ushort_t* ctx = (ushort_t*)(wsb + (48ull << 20));
  ushort_t* ff  = q;  // 32 MB alias over q/k/v/vt (dead after attention)
  ushort_t* n1b = (ushort_t*)(wsb + (56ull << 20));
  ushort_t* xbf = (ushort_t*)(wsb + (64ull << 20));
  ushort_t* wqb = (ushort_t*)(wsb + (72ull << 20));
  ushort_t* wkb = wqb + 3 * 4096;
  ushort_t* wvb = wkb + 3 * 4096;
  ushort_t* wob = (ushort_t*)(wsb + (73ull << 20));      // 6 MB
  ushort_t* w1b = (ushort_t*)(wsb + (80ull << 20));      // 24 MB
  ushort_t* w2b = (ushort_t*)(wsb + (104ull << 20));     // 24 MB

  auto conv = [&](const float* s, ushort_t* d, long n) {
    int n8 = (int)(n / 8);
    int g = (n8 + 255) / 256;
    if (g > 2048) g = 2048;
    conv_bf16<<<g, 256, 0, stream>>>(s, d, n8);
  };
  conv(x, xbf, 4194304);
  conv(Wq, wqb, 3 * 4096);
  conv(Wk, wkb, 3 * 4096);
  conv(Wv, wvb, 3 * 4096);
  conv(Wo, wob, 3ll * 1048576);
  conv(W1, w1b, 3ll * 4194304);
  conv(W2, w2b, 3ll * 4194304);

  const ushort_t* curb = xbf;
  const float* curf = x;
  for (int l = 0; l < 3; ++l) {
    qkv_kernel<<<512, 256, 0, stream>>>(curb, wqb + l * 4096, wkb + l * 4096,
                                        wvb + l * 4096, q, k, v);
    vtrans<<<dim3(32, 16, 2), 256, 0, stream>>>(v, vt);
    attn2<<<dim3(32, 32), 256, 0, stream>>>(q, k, vt, ctx);
    // att_out = ctx @ Wo^T + bo + residual -> t0 (fp32)
    gemm_bf16<128, 64, false, 3, true><<<dim3(16, 32), 256, 0, stream>>>(
        ctx, wob + (size_t)l * 1048576, bo + l * 1024, curf, t0, 4096, 1024,
        1024);
    ln_dual<<<4096, 256, 0, stream>>>(t0, ln1g + l * 1024, ln1b + l * 1024,
                                      out, n1b);
    // ff = relu(n1 @ W1^T + b1) -> bf16
    gemm_bf16<128, 128, true, 5, true><<<dim3(32, 32), 256, 0, stream>>>(
        n1b, w1b + (size_t)l * 4194304, b1 + l * 4096, nullptr, ff, 4096, 4096,
        1024);
    // t0 = ff @ W2^T + b2 + n1 (fp32)
    gemm_bf16<128, 64, false, 3, true><<<dim3(16, 32), 256, 0, stream>>>(
        ff, w2b + (size_t)l * 4194304, b2 + l * 1024, out, t0, 4096, 1024,
        4096);
    ln_dual<<<4096, 256, 0, stream>>>(t0, ln2g + l * 1024, ln2b + l * 1024,
                                      out, xbf);
    curb = xbf;
    curf = out;
  }
}